// Round 5
// baseline (237.098 us; speedup 1.0000x reference)
//
#include <hip/hip_runtime.h>
#include <hip/hip_bf16.h>
#include <math.h>

// Pipeline: y = LN(x + gelu(Q(gelu(x@W1+b1)@W2+b2)@W3+b3)@W4+b4)
// Round 5:
//  - gemm4_ln v2: x residual prefetched to registers (float4, coalesced)
//    BEFORE the K-loop; y routed through LDS tile (stride 772 -> 2-way banks
//    = free) so residual-add/LN/store all run as coalesced float4.
//  - gemm1_feats v2: BM 64->32, grid 512 (2 blocks/CU) for latency hiding.
//  - quantum v3 unchanged.

typedef __attribute__((ext_vector_type(8))) short bf16x8;
typedef __attribute__((ext_vector_type(4))) float f32x4;

__device__ __forceinline__ float gelu_f(float x) {
    return 0.5f * x * (1.0f + erff(x * 0.70710678118654752f));
}

__device__ __forceinline__ short f2b(float x) {
    __hip_bfloat16 h = __float2bfloat16(x);
    return reinterpret_cast<short&>(h);
}

__device__ __forceinline__ short4 f4_to_b4(float4 v) {
    return make_short4(f2b(v.x), f2b(v.y), f2b(v.z), f2b(v.w));
}

// ---------------------------------------------------------------------------
// 32x32 tiled transpose fp32[K][N] -> bf16[N][K]
// ---------------------------------------------------------------------------
__global__ __launch_bounds__(256) void transpose_bf16_kernel(
    const float* __restrict__ in, short* __restrict__ out, int K, int N)
{
    __shared__ float tl[32][33];
    const int k0 = blockIdx.y * 32, n0 = blockIdx.x * 32;
    const int r = threadIdx.x >> 3, c4 = (threadIdx.x & 7) * 4;
    const float4 v = *(const float4*)(in + (size_t)(k0 + r) * N + n0 + c4);
    tl[r][c4] = v.x; tl[r][c4 + 1] = v.y; tl[r][c4 + 2] = v.z; tl[r][c4 + 3] = v.w;
    __syncthreads();
    short4 o = make_short4(f2b(tl[c4][r]), f2b(tl[c4 + 1][r]),
                           f2b(tl[c4 + 2][r]), f2b(tl[c4 + 3][r]));
    *(short4*)(out + (size_t)(n0 + r) * K + k0 + c4) = o;
}

// ---------------------------------------------------------------------------
// setup: Cg[16][8] = RZ(w2)RY(w1)RZ(w0) per (layer,wire); W2T[16][256] bf16
// ---------------------------------------------------------------------------
__global__ __launch_bounds__(256) void setup_kernel(
    const float* __restrict__ qw, const float* __restrict__ W2,
    float* __restrict__ Cg, short* __restrict__ W2T)
{
    const int t = threadIdx.x;
    if (t < 16) {
        const float w0 = qw[t * 3 + 0];
        const float w1 = qw[t * 3 + 1];
        const float w2 = qw[t * 3 + 2];
        const float a0 = 0.5f * w0, a2 = 0.5f * w2;
        float s1, c1; sincosf(0.5f * w1, &s1, &c1);
        float sp, cp; sincosf(a0 + a2, &sp, &cp);
        float sm, cm; sincosf(a0 - a2, &sm, &cm);
        Cg[t * 8 + 0] =  c1 * cp;  Cg[t * 8 + 1] = -c1 * sp;
        Cg[t * 8 + 2] = -s1 * cm;  Cg[t * 8 + 3] = -s1 * sm;
        Cg[t * 8 + 4] =  s1 * cm;  Cg[t * 8 + 5] = -s1 * sm;
        Cg[t * 8 + 6] =  c1 * cp;  Cg[t * 8 + 7] =  c1 * sp;
    }
    for (int idx = t; idx < 16 * 256; idx += 256) {
        const int n = idx & 15, k = idx >> 4;
        W2T[(size_t)n * 256 + k] = (n < 8) ? f2b(W2[(size_t)k * 8 + n]) : (short)0;
    }
}

// ---------------------------------------------------------------------------
// GEMM1+feats: feats[M,8] = gelu(x[M,768]@W1+b1)@W2 + b2
// BM=32, BN=256(full), BK=32, 256 thr = 4 waves (wave = 64-col n-range).
// Double-buffered A staging, 2-deep register prefetch. Grid: M/32.
// ---------------------------------------------------------------------------
__global__ __launch_bounds__(256) void gemm1_feats_kernel(
    const float* __restrict__ x, const short* __restrict__ W1bt,
    const float* __restrict__ b1, const short* __restrict__ W2T,
    const float* __restrict__ b2, float* __restrict__ feats, int M)
{
    __shared__ short As[2][32][40];    // [buf][m][k], stride 40: <=2-way banks
    __shared__ short hb[32][264];      // gelu(h) block, [m][n]

    const int tid = threadIdx.x;
    const int wid = tid >> 6, L = tid & 63;
    const int quad = L >> 4, r16 = L & 15;
    const int nw = wid;
    const int m0 = blockIdx.x * 32;

    const int m_s = tid >> 3, k_s = (tid & 7) << 2;
    const float* xp = x + (size_t)(m0 + m_s) * 768 + k_s;

    const short* bp = W1bt + (size_t)(nw * 64 + r16) * 768 + quad * 8;

    f32x4 acc[2][4];
    #pragma unroll
    for (int i = 0; i < 2; ++i)
        #pragma unroll
        for (int j = 0; j < 4; ++j) acc[i][j] = (f32x4){0.f, 0.f, 0.f, 0.f};

    float4 v0 = *(const float4*)(xp);
    *(short4*)&As[0][m_s][k_s] = f4_to_b4(v0);
    float4 v1 = *(const float4*)(xp + 32);
    __syncthreads();

    for (int kt = 0; kt < 24; ++kt) {
        const int buf = kt & 1;
        float4 vn = v1;
        if (kt + 2 < 24) vn = *(const float4*)(xp + (kt + 2) * 32);

        const bf16x8 a0 = *(const bf16x8*)&As[buf][r16][quad * 8];
        const bf16x8 a1 = *(const bf16x8*)&As[buf][16 + r16][quad * 8];
        #pragma unroll
        for (int nt = 0; nt < 4; ++nt) {
            const bf16x8 bfr = *(const bf16x8*)(bp + (size_t)nt * 16 * 768 + kt * 32);
            acc[0][nt] = __builtin_amdgcn_mfma_f32_16x16x32_bf16(a0, bfr, acc[0][nt], 0, 0, 0);
            acc[1][nt] = __builtin_amdgcn_mfma_f32_16x16x32_bf16(a1, bfr, acc[1][nt], 0, 0, 0);
        }
        if (kt + 1 < 24) {
            *(short4*)&As[buf ^ 1][m_s][k_s] = f4_to_b4(v1);
        }
        __syncthreads();
        v1 = vn;
    }

    // epilogue: gelu + bias -> hb (bf16)
    #pragma unroll
    for (int mt = 0; mt < 2; ++mt) {
        #pragma unroll
        for (int nt = 0; nt < 4; ++nt) {
            const int n = nw * 64 + nt * 16 + r16;
            const float bv = b1[n];
            #pragma unroll
            for (int reg = 0; reg < 4; ++reg) {
                const int rrow = 16 * mt + quad * 4 + reg;
                hb[rrow][n] = f2b(gelu_f(acc[mt][nt][reg] + bv));
            }
        }
    }
    __syncthreads();

    // feats = hb @ W2T^T + b2 : waves 0..1, wave = m-tile
    if (wid < 2) {
        const int mt = wid;
        f32x4 fa = (f32x4){0.f, 0.f, 0.f, 0.f};
        #pragma unroll
        for (int kt = 0; kt < 8; ++kt) {
            const bf16x8 ha = *(const bf16x8*)&hb[16 * mt + r16][kt * 32 + quad * 8];
            const bf16x8 wb = *(const bf16x8*)(W2T + (size_t)r16 * 256 + kt * 32 + quad * 8);
            fa = __builtin_amdgcn_mfma_f32_16x16x32_bf16(ha, wb, fa, 0, 0, 0);
        }
        if (r16 < 8) {
            const float bv = b2[r16];
            #pragma unroll
            for (int reg = 0; reg < 4; ++reg) {
                const int row = m0 + 16 * mt + quad * 4 + reg;
                feats[(size_t)row * 8 + r16] = fa[reg] + bv;
            }
        }
    }
}

// ---------------------------------------------------------------------------
// Quantum v3 (unchanged): one wave per row; composed CNOT permutation.
// ---------------------------------------------------------------------------
__global__ __launch_bounds__(256) void quantum_kernel(
    const float* __restrict__ feats, const float* __restrict__ Cg,
    const float* __restrict__ W3, const float* __restrict__ b3,
    short* __restrict__ ebt)
{
    const int t = threadIdx.x;
    const int wid = t >> 6, L = t & 63;
    const int row = blockIdx.x * 4 + wid;

    const float fv = feats[(size_t)row * 8 + (L & 7)];
    float sv, cv;
    sincosf(0.5f * fv, &sv, &cv);
    float cf[8], sf[8];
    #pragma unroll
    for (int w = 0; w < 8; ++w) {
        cf[w] = __shfl(cv, w, 64);
        sf[w] = __shfl(sv, w, 64);
    }

    float re[4], im[4];
    #pragma unroll
    for (int r = 0; r < 4; ++r) { re[r] = 0.0f; im[r] = 0.0f; }
    re[0] = (L == 0) ? 1.0f : 0.0f;

    const int G = L ^ (L >> 1);
    const int mapB = G ^ 48;
    const bool par = __popc(L) & 1;

    #pragma unroll
    for (int l = 0; l < 2; ++l) {
        #pragma unroll
        for (int w = 0; w < 8; ++w) {
            const float* Cw = Cg + (l * 8 + w) * 8;
            const float c0 = Cw[0], c1 = Cw[1], c2 = Cw[2], c3 = Cw[3];
            const float c4 = Cw[4], c5 = Cw[5], c6 = Cw[6], c7 = Cw[7];
            const float U00r = cf[w]*c0 + sf[w]*c2, U00i = cf[w]*c1 + sf[w]*c3;
            const float U01r = cf[w]*c2 - sf[w]*c0, U01i = cf[w]*c3 - sf[w]*c1;
            const float U10r = cf[w]*c4 + sf[w]*c6, U10i = cf[w]*c5 + sf[w]*c7;
            const float U11r = cf[w]*c6 - sf[w]*c4, U11i = cf[w]*c7 - sf[w]*c5;

            if (w <= 5) {
                const int kb = 5 - w;
                const int xm = 1 << kb;
                const bool hi = (L >> kb) & 1;
                const float u0r = hi ? U11r : U00r;
                const float u0i = hi ? U11i : U00i;
                const float u1r = hi ? U10r : U01r;
                const float u1i = hi ? U10i : U01i;
                #pragma unroll
                for (int r = 0; r < 4; ++r) {
                    const float ore = __shfl_xor(re[r], xm, 64);
                    const float oim = __shfl_xor(im[r], xm, 64);
                    const float nre = u0r*re[r] - u0i*im[r] + u1r*ore - u1i*oim;
                    const float nim = u0r*im[r] + u0i*re[r] + u1r*oim + u1i*ore;
                    re[r] = nre; im[r] = nim;
                }
            } else if (w == 6) {
                float nre[4], nim[4];
                #pragma unroll
                for (int p = 0; p < 2; ++p) {
                    nre[p]   = U00r*re[p]-U00i*im[p] + U01r*re[p+2]-U01i*im[p+2];
                    nim[p]   = U00r*im[p]+U00i*re[p] + U01r*im[p+2]+U01i*re[p+2];
                    nre[p+2] = U10r*re[p]-U10i*im[p] + U11r*re[p+2]-U11i*im[p+2];
                    nim[p+2] = U10r*im[p]+U10i*re[p] + U11r*im[p+2]+U11i*re[p+2];
                }
                #pragma unroll
                for (int r = 0; r < 4; ++r) { re[r] = nre[r]; im[r] = nim[r]; }
            } else {
                float nre[4], nim[4];
                #pragma unroll
                for (int p = 0; p < 4; p += 2) {
                    nre[p]   = U00r*re[p]-U00i*im[p] + U01r*re[p+1]-U01i*im[p+1];
                    nim[p]   = U00r*im[p]+U00i*re[p] + U01r*im[p+1]+U01i*re[p+1];
                    nre[p+1] = U10r*re[p]-U10i*im[p] + U11r*re[p+1]-U11i*im[p+1];
                    nim[p+1] = U10r*im[p]+U10i*re[p] + U11r*im[p+1]+U11i*re[p+1];
                }
                #pragma unroll
                for (int r = 0; r < 4; ++r) { re[r] = nre[r]; im[r] = nim[r]; }
            }
        }

        {
            const float s0r = par ? re[2] : re[0], s0i = par ? im[2] : im[0];
            const float s1r = par ? re[3] : re[1], s1i = par ? im[3] : im[1];
            const float s2r = par ? re[1] : re[3], s2i = par ? im[1] : im[3];
            const float s3r = par ? re[0] : re[2], s3i = par ? im[0] : im[2];
            re[0] = __shfl(s0r, G, 64);    im[0] = __shfl(s0i, G, 64);
            re[1] = __shfl(s1r, mapB, 64); im[1] = __shfl(s1i, mapB, 64);
            re[2] = __shfl(s2r, G, 64);    im[2] = __shfl(s2i, G, 64);
            re[3] = __shfl(s3r, mapB, 64); im[3] = __shfl(s3i, mapB, 64);
        }
    }

    const float p0 = re[0]*re[0] + im[0]*im[0];
    const float p1 = re[1]*re[1] + im[1]*im[1];
    const float p2 = re[2]*re[2] + im[2]*im[2];
    const float p3 = re[3]*re[3] + im[3]*im[3];
    const float pt = p0 + p1 + p2 + p3;
    float v[8];
    #pragma unroll
    for (int w = 0; w < 6; ++w) v[w] = ((L >> (5 - w)) & 1) ? -pt : pt;
    v[6] = p0 + p1 - p2 - p3;
    v[7] = p0 - p1 + p2 - p3;
    #pragma unroll
    for (int j = 0; j < 4; ++j) {
        const float send = (L & 1) ? v[j] : v[j + 4];
        const float keep = (L & 1) ? v[j + 4] : v[j];
        v[j] = keep + __shfl_xor(send, 1, 64);
    }
    #pragma unroll
    for (int j = 0; j < 2; ++j) {
        const float send = (L & 2) ? v[j] : v[j + 2];
        const float keep = (L & 2) ? v[j + 2] : v[j];
        v[j] = keep + __shfl_xor(send, 2, 64);
    }
    {
        const float send = (L & 4) ? v[0] : v[1];
        const float keep = (L & 4) ? v[1] : v[0];
        v[0] = keep + __shfl_xor(send, 4, 64);
    }
    v[0] += __shfl_xor(v[0], 8, 64);
    v[0] += __shfl_xor(v[0], 16, 64);
    v[0] += __shfl_xor(v[0], 32, 64);
    float z[8];
    #pragma unroll
    for (int w = 0; w < 8; ++w) {
        const int src = ((w & 1) << 2) | (w & 2) | ((w >> 2) & 1);
        z[w] = __shfl(v[0], src, 64);
    }

    const float4 b3v = *(const float4*)(b3 + 4 * L);
    float acc[4] = {b3v.x, b3v.y, b3v.z, b3v.w};
    #pragma unroll
    for (int w = 0; w < 8; ++w) {
        const float4 w3v = *(const float4*)(W3 + (size_t)w * 256 + 4 * L);
        acc[0] += z[w] * w3v.x; acc[1] += z[w] * w3v.y;
        acc[2] += z[w] * w3v.z; acc[3] += z[w] * w3v.w;
    }
    *(short4*)(ebt + (size_t)row * 256 + 4 * L) =
        make_short4(f2b(gelu_f(acc[0])), f2b(gelu_f(acc[1])),
                    f2b(gelu_f(acc[2])), f2b(gelu_f(acc[3])));
}

// ---------------------------------------------------------------------------
// GEMM4+LN v2: y = e[M,256]@W4 + b4 + x ; out = LN(y)*gamma + beta
// BM=16, BN=768(full row), K=256 staged once. x prefetched to registers
// (float4 coalesced) before the K-loop; y routed through LDS (stride 772 ->
// 2-way banks = free); residual/LN/store phase is fully coalesced float4.
// Grid: M/16, 256 thr.
// ---------------------------------------------------------------------------
__global__ __launch_bounds__(256) void gemm4_ln_kernel(
    const short* __restrict__ ebt, const short* __restrict__ W4bt,
    const float* __restrict__ b4, const float* __restrict__ x,
    const float* __restrict__ gamma, const float* __restrict__ beta,
    float* __restrict__ out, int M)
{
    __shared__ short Ae[16][264];
    __shared__ float yb[16][772];   // stride 772: quad rows offset 16 banks

    const int tid = threadIdx.x;
    const int wv = tid >> 6, L = tid & 63;
    const int quad = L >> 4, r16 = L & 15;
    const int m0 = blockIdx.x * 16;
    const int n0 = wv * 192;

    // ---- coalesced x prefetch: thread -> row=tid>>4, 12 float4 at stride 64
    const int prow = tid >> 4, pcb = (tid & 15) * 4;
    const float* xrow = x + (size_t)(m0 + prow) * 768 + pcb;
    float4 xr[12];
    #pragma unroll
    for (int c = 0; c < 12; ++c) xr[c] = *(const float4*)(xrow + 64 * c);

    // ---- stage e (bf16) to LDS
    {
        const int m_s = tid >> 4, k16 = (tid & 15) * 16;
        const int4* ep = (const int4*)(ebt + (size_t)(m0 + m_s) * 256 + k16);
        const int4 e0 = ep[0], e1 = ep[1];
        *(int4*)&Ae[m_s][k16] = e0;
        *(int4*)&Ae[m_s][k16 + 8] = e1;
    }
    __syncthreads();

    const short* bp = W4bt + (size_t)(n0 + r16) * 256 + quad * 8;

    f32x4 acc[12];
    #pragma unroll
    for (int nt = 0; nt < 12; ++nt) acc[nt] = (f32x4){0.f, 0.f, 0.f, 0.f};

    for (int kt = 0; kt < 8; ++kt) {
        const bf16x8 af = *(const bf16x8*)&Ae[r16][kt * 32 + quad * 8];
        #pragma unroll
        for (int nt = 0; nt < 12; ++nt) {
            const bf16x8 bfr = *(const bf16x8*)(bp + (size_t)nt * 16 * 256 + kt * 32);
            acc[nt] = __builtin_amdgcn_mfma_f32_16x16x32_bf16(af, bfr, acc[nt], 0, 0, 0);
        }
    }

    // ---- C-layout -> LDS
    #pragma unroll
    for (int nt = 0; nt < 12; ++nt) {
        const int n = n0 + nt * 16 + r16;
        #pragma unroll
        for (int reg = 0; reg < 4; ++reg) {
            yb[quad * 4 + reg][n] = acc[nt][reg];
        }
    }
    __syncthreads();

    // ---- coalesced residual + LN + store
    float4 yv[12];
    float s = 0.f, q = 0.f;
    #pragma unroll
    for (int c = 0; c < 12; ++c) {
        const float4 b4v = *(const float4*)(b4 + pcb + 64 * c);
        float4 y = *(const float4*)&yb[prow][pcb + 64 * c];
        y.x += xr[c].x + b4v.x;
        y.y += xr[c].y + b4v.y;
        y.z += xr[c].z + b4v.z;
        y.w += xr[c].w + b4v.w;
        yv[c] = y;
        s += y.x + y.y + y.z + y.w;
        q += y.x * y.x + y.y * y.y + y.z * y.z + y.w * y.w;
    }
    // row lives in one wave: lanes (quad*16..quad*16+15); reduce 16 lanes
    #pragma unroll
    for (int off = 1; off < 16; off <<= 1) {
        s += __shfl_xor(s, off, 64);
        q += __shfl_xor(q, off, 64);
    }
    const float mu = s * (1.0f / 768.0f);
    const float var = q * (1.0f / 768.0f) - mu * mu;
    const float rstd = rsqrtf(var + 1e-5f);

    float* orow = out + (size_t)(m0 + prow) * 768 + pcb;
    #pragma unroll
    for (int c = 0; c < 12; ++c) {
        const float4 gv = *(const float4*)(gamma + pcb + 64 * c);
        const float4 bv = *(const float4*)(beta + pcb + 64 * c);
        float4 o;
        o.x = gv.x * (yv[c].x - mu) * rstd + bv.x;
        o.y = gv.y * (yv[c].y - mu) * rstd + bv.y;
        o.z = gv.z * (yv[c].z - mu) * rstd + bv.z;
        o.w = gv.w * (yv[c].w - mu) * rstd + bv.w;
        *(float4*)(orow + 64 * c) = o;
    }
}

extern "C" void kernel_launch(void* const* d_in, const int* in_sizes, int n_in,
                              void* d_out, int out_size, void* d_ws, size_t ws_size,
                              hipStream_t stream) {
    (void)n_in; (void)out_size; (void)ws_size;
    const float* x     = (const float*)d_in[0];
    const float* W1    = (const float*)d_in[1];
    const float* b1    = (const float*)d_in[2];
    const float* W2    = (const float*)d_in[3];
    const float* b2    = (const float*)d_in[4];
    const float* qw    = (const float*)d_in[5];
    const float* W3    = (const float*)d_in[6];
    const float* b3    = (const float*)d_in[7];
    const float* W4    = (const float*)d_in[8];
    const float* b4    = (const float*)d_in[9];
    const float* gamma = (const float*)d_in[10];
    const float* beta  = (const float*)d_in[11];
    float* out = (float*)d_out;

    const int D = 768, H = 256;
    const int B = in_sizes[0] / D;                       // 16384

    short* W1bt  = (short*)d_ws;                         // 256x768 bf16
    short* W4bt  = W1bt + (size_t)H * D;                 // 768x256 bf16
    short* W2T   = W4bt + (size_t)D * H;                 // 16x256 bf16
    float* Cg    = (float*)(W2T + 16 * 256);             // 16x8 f32
    float* feats = Cg + 128;                             // Bx8 f32
    short* ebt   = (short*)(feats + (size_t)B * 8);      // Bx256 bf16

    transpose_bf16_kernel<<<dim3(H / 32, D / 32), 256, 0, stream>>>(W1, W1bt, D, H);
    transpose_bf16_kernel<<<dim3(D / 32, H / 32), 256, 0, stream>>>(W4, W4bt, H, D);
    setup_kernel<<<1, 256, 0, stream>>>(qw, W2, Cg, W2T);
    gemm1_feats_kernel<<<dim3(B / 32), 256, 0, stream>>>(x, W1bt, b1, W2T, b2, feats, B);
    quantum_kernel<<<dim3(B / 4), 256, 0, stream>>>(feats, Cg, W3, b3, ebt);
    gemm4_ln_kernel<<<dim3(B / 16), 256, 0, stream>>>(ebt, W4bt, b4, x, gamma, beta, out, B);
}

// Round 6
// 209.354 us; speedup vs baseline: 1.1325x; 1.1325x over previous
//
#include <hip/hip_runtime.h>
#include <hip/hip_bf16.h>
#include <math.h>

// Pipeline: y = LN(x + gelu(Q(gelu(x@W1+b1)@W2+b2)@W3+b3)@W4+b4)
// Round 6: TWO dispatches.
//  prep_kernel: W1/W4 -> bf16 transposed + quantum gate matrices + W2T.
//  fused_kernel: per 32-row stripe: gemm1 -> feats -> quantum (8 rows/wave)
//    -> e in LDS (hi/lo bf16) -> gemm4 -> residual+LN. 512 blocks, 2/CU,
//    whole grid resident; no global intermediates.
//  Precision: A-side hi/lo bf16 split on both GEMMs (exact fp32 split; only
//  W-side bf16 error remains).

typedef __attribute__((ext_vector_type(8))) short bf16x8;
typedef __attribute__((ext_vector_type(4))) float f32x4;

__device__ __forceinline__ float gelu_f(float x) {
    return 0.5f * x * (1.0f + erff(x * 0.70710678118654752f));
}

__device__ __forceinline__ short f2b(float x) {
    __hip_bfloat16 h = __float2bfloat16(x);
    return reinterpret_cast<short&>(h);
}

__device__ __forceinline__ float b2f(short s) {
    union { unsigned u; float f; } c;
    c.u = ((unsigned)(unsigned short)s) << 16;
    return c.f;
}

__device__ __forceinline__ short4 f4_to_b4(float4 v) {
    return make_short4(f2b(v.x), f2b(v.y), f2b(v.z), f2b(v.w));
}

// exact two-term split: v = hi + lo (hi = bf16 RN, lo = bf16 of residual)
__device__ __forceinline__ void split4(float4 v, short4& hi, short4& lo) {
    hi = f4_to_b4(v);
    lo = make_short4(f2b(v.x - b2f(hi.x)), f2b(v.y - b2f(hi.y)),
                     f2b(v.z - b2f(hi.z)), f2b(v.w - b2f(hi.w)));
}

// ---------------------------------------------------------------------------
// prep: both weight transposes (fp32[K][N] -> bf16[N][K]) + Cg + W2T.
// grid 385: [0,192) W1 tiles, [192,384) W4 tiles, 384 setup.
// ---------------------------------------------------------------------------
__global__ __launch_bounds__(256) void prep_kernel(
    const float* __restrict__ W1, const float* __restrict__ W4,
    const float* __restrict__ qw, const float* __restrict__ W2,
    short* __restrict__ W1bt, short* __restrict__ W4bt,
    short* __restrict__ W2T, float* __restrict__ Cg)
{
    __shared__ float tl[32][33];
    const int i = blockIdx.x, t = threadIdx.x;
    if (i < 384) {
        const float* in; short* outp; int K, N, k0, n0;
        if (i < 192) {                 // W1 [768][256] -> W1bt [256][768]
            in = W1; outp = W1bt; K = 768; N = 256;
            k0 = (i >> 3) * 32; n0 = (i & 7) * 32;
        } else {                       // W4 [256][768] -> W4bt [768][256]
            const int j = i - 192;
            in = W4; outp = W4bt; K = 256; N = 768;
            k0 = (j & 7) * 32; n0 = (j >> 3) * 32;
        }
        const int r = t >> 3, c4 = (t & 7) * 4;
        const float4 v = *(const float4*)(in + (size_t)(k0 + r) * N + n0 + c4);
        tl[r][c4] = v.x; tl[r][c4 + 1] = v.y; tl[r][c4 + 2] = v.z; tl[r][c4 + 3] = v.w;
        __syncthreads();
        short4 o = make_short4(f2b(tl[c4][r]), f2b(tl[c4 + 1][r]),
                               f2b(tl[c4 + 2][r]), f2b(tl[c4 + 3][r]));
        *(short4*)(outp + (size_t)(n0 + r) * K + k0 + c4) = o;
    } else {
        if (t < 16) {
            const float w0 = qw[t * 3 + 0];
            const float w1 = qw[t * 3 + 1];
            const float w2 = qw[t * 3 + 2];
            const float a0 = 0.5f * w0, a2 = 0.5f * w2;
            float s1, c1; sincosf(0.5f * w1, &s1, &c1);
            float sp, cp; sincosf(a0 + a2, &sp, &cp);   // e^{-i(a0+a2)} = cp - i sp
            float sm, cm; sincosf(a0 - a2, &sm, &cm);   // e^{+i(a0-a2)} = cm + i sm
            Cg[t * 8 + 0] =  c1 * cp;  Cg[t * 8 + 1] = -c1 * sp;   // C00
            Cg[t * 8 + 2] = -s1 * cm;  Cg[t * 8 + 3] = -s1 * sm;   // C01
            Cg[t * 8 + 4] =  s1 * cm;  Cg[t * 8 + 5] = -s1 * sm;   // C10
            Cg[t * 8 + 6] =  c1 * cp;  Cg[t * 8 + 7] =  c1 * sp;   // C11
        }
        for (int idx = t; idx < 16 * 256; idx += 256) {
            const int n = idx & 15, k = idx >> 4;
            W2T[(size_t)n * 256 + k] = (n < 8) ? f2b(W2[(size_t)k * 8 + n]) : (short)0;
        }
    }
}

// ---------------------------------------------------------------------------
// fused main: one block = 32 batch rows, 256 thr = 4 waves, 2 blocks/CU.
// ---------------------------------------------------------------------------
__global__ __launch_bounds__(256, 2) void fused_kernel(
    const float* __restrict__ x, const short* __restrict__ W1bt,
    const float* __restrict__ b1, const short* __restrict__ W2T,
    const float* __restrict__ b2, const float* __restrict__ Cg,
    const float* __restrict__ W3, const float* __restrict__ b3,
    const short* __restrict__ W4bt, const float* __restrict__ b4,
    const float* __restrict__ gamma, const float* __restrict__ beta,
    float* __restrict__ out)
{
    __shared__ short Ash[2][32][40];   // x-tile hi (stride 40 -> <=2-way banks)
    __shared__ short Asl[2][32][40];   // x-tile lo
    __shared__ short hb[32][264];      // gelu(h) bf16
    __shared__ short ehi[32][264];     // e hi
    __shared__ short elo[32][264];     // e lo
    __shared__ float feats_s[32][8];
    __shared__ float red[4][32][2];
    __shared__ float stats_s[32][2];

    const int tid = threadIdx.x;
    const int wid = tid >> 6, L = tid & 63;
    const int quad = L >> 4, r16 = L & 15;
    const int m0 = blockIdx.x * 32;

    // ================= phase 1: h = gelu(x@W1+b1) (hi/lo bf16 MFMA) =========
    {
        const int m_s = tid >> 3, k_s = (tid & 7) << 2;
        const float* xp = x + (size_t)(m0 + m_s) * 768 + k_s;
        const short* bp = W1bt + (size_t)(wid * 64 + r16) * 768 + quad * 8;

        f32x4 acc[2][4];
        #pragma unroll
        for (int i = 0; i < 2; ++i)
            #pragma unroll
            for (int j = 0; j < 4; ++j) acc[i][j] = (f32x4){0.f, 0.f, 0.f, 0.f};

        float4 v0 = *(const float4*)(xp);
        {
            short4 hi, lo; split4(v0, hi, lo);
            *(short4*)&Ash[0][m_s][k_s] = hi;
            *(short4*)&Asl[0][m_s][k_s] = lo;
        }
        float4 v1 = *(const float4*)(xp + 32);
        __syncthreads();

        for (int kt = 0; kt < 24; ++kt) {
            const int buf = kt & 1;
            float4 vn = v1;
            if (kt + 2 < 24) vn = *(const float4*)(xp + (kt + 2) * 32);

            const bf16x8 a0h = *(const bf16x8*)&Ash[buf][r16][quad * 8];
            const bf16x8 a0l = *(const bf16x8*)&Asl[buf][r16][quad * 8];
            const bf16x8 a1h = *(const bf16x8*)&Ash[buf][16 + r16][quad * 8];
            const bf16x8 a1l = *(const bf16x8*)&Asl[buf][16 + r16][quad * 8];
            #pragma unroll
            for (int nt = 0; nt < 4; ++nt) {
                const bf16x8 bfr = *(const bf16x8*)(bp + (size_t)nt * 16 * 768 + kt * 32);
                acc[0][nt] = __builtin_amdgcn_mfma_f32_16x16x32_bf16(a0h, bfr, acc[0][nt], 0, 0, 0);
                acc[0][nt] = __builtin_amdgcn_mfma_f32_16x16x32_bf16(a0l, bfr, acc[0][nt], 0, 0, 0);
                acc[1][nt] = __builtin_amdgcn_mfma_f32_16x16x32_bf16(a1h, bfr, acc[1][nt], 0, 0, 0);
                acc[1][nt] = __builtin_amdgcn_mfma_f32_16x16x32_bf16(a1l, bfr, acc[1][nt], 0, 0, 0);
            }
            if (kt + 1 < 24) {
                short4 hi, lo; split4(v1, hi, lo);
                *(short4*)&Ash[buf ^ 1][m_s][k_s] = hi;
                *(short4*)&Asl[buf ^ 1][m_s][k_s] = lo;
            }
            __syncthreads();
            v1 = vn;
        }

        // gelu + bias -> hb
        #pragma unroll
        for (int mt = 0; mt < 2; ++mt) {
            #pragma unroll
            for (int nt = 0; nt < 4; ++nt) {
                const int n = wid * 64 + nt * 16 + r16;
                const float bv = b1[n];
                #pragma unroll
                for (int reg = 0; reg < 4; ++reg) {
                    hb[16 * mt + quad * 4 + reg][n] = f2b(gelu_f(acc[mt][nt][reg] + bv));
                }
            }
        }
    }
    __syncthreads();

    // ================= phase 2: feats = hb@W2 + b2 ==========================
    if (wid < 2) {
        const int mt = wid;
        f32x4 fa = (f32x4){0.f, 0.f, 0.f, 0.f};
        #pragma unroll
        for (int kt = 0; kt < 8; ++kt) {
            const bf16x8 ha = *(const bf16x8*)&hb[16 * mt + r16][kt * 32 + quad * 8];
            const bf16x8 wb = *(const bf16x8*)(W2T + (size_t)r16 * 256 + kt * 32 + quad * 8);
            fa = __builtin_amdgcn_mfma_f32_16x16x32_bf16(ha, wb, fa, 0, 0, 0);
        }
        if (r16 < 8) {
            const float bv = b2[r16];
            #pragma unroll
            for (int reg = 0; reg < 4; ++reg) {
                feats_s[16 * mt + quad * 4 + reg][r16] = fa[reg] + bv;
            }
        }
    }
    __syncthreads();

    // ================= phase 3: quantum, 8 rows per wave ====================
    {
        float4 w3r[8];
        #pragma unroll
        for (int w = 0; w < 8; ++w) w3r[w] = *(const float4*)(W3 + (size_t)w * 256 + 4 * L);
        const float4 b3v = *(const float4*)(b3 + 4 * L);

        const int G = L ^ (L >> 1);
        const int mapB = G ^ 48;
        const bool par = __popc(L) & 1;

        #pragma unroll 1
        for (int rr = 0; rr < 8; ++rr) {
            const int row = wid * 8 + rr;
            const float fv = feats_s[row][L & 7];
            float sv, cv;
            sincosf(0.5f * fv, &sv, &cv);
            float cf[8], sf[8];
            #pragma unroll
            for (int w = 0; w < 8; ++w) {
                cf[w] = __shfl(cv, w, 64);
                sf[w] = __shfl(sv, w, 64);
            }

            float re[4], im[4];
            #pragma unroll
            for (int r = 0; r < 4; ++r) { re[r] = 0.0f; im[r] = 0.0f; }
            re[0] = (L == 0) ? 1.0f : 0.0f;

            #pragma unroll
            for (int l = 0; l < 2; ++l) {
                #pragma unroll
                for (int w = 0; w < 8; ++w) {
                    const float* Cw = Cg + (l * 8 + w) * 8;
                    const float c0 = Cw[0], c1 = Cw[1], c2 = Cw[2], c3 = Cw[3];
                    const float c4 = Cw[4], c5 = Cw[5], c6 = Cw[6], c7 = Cw[7];
                    const float U00r = cf[w]*c0 + sf[w]*c2, U00i = cf[w]*c1 + sf[w]*c3;
                    const float U01r = cf[w]*c2 - sf[w]*c0, U01i = cf[w]*c3 - sf[w]*c1;
                    const float U10r = cf[w]*c4 + sf[w]*c6, U10i = cf[w]*c5 + sf[w]*c7;
                    const float U11r = cf[w]*c6 - sf[w]*c4, U11i = cf[w]*c7 - sf[w]*c5;

                    if (w <= 5) {
                        const int kb = 5 - w;
                        const int xm = 1 << kb;
                        const bool hi = (L >> kb) & 1;
                        const float u0r = hi ? U11r : U00r;
                        const float u0i = hi ? U11i : U00i;
                        const float u1r = hi ? U10r : U01r;
                        const float u1i = hi ? U10i : U01i;
                        #pragma unroll
                        for (int r = 0; r < 4; ++r) {
                            const float ore = __shfl_xor(re[r], xm, 64);
                            const float oim = __shfl_xor(im[r], xm, 64);
                            const float nre = u0r*re[r] - u0i*im[r] + u1r*ore - u1i*oim;
                            const float nim = u0r*im[r] + u0i*re[r] + u1r*oim + u1i*ore;
                            re[r] = nre; im[r] = nim;
                        }
                    } else if (w == 6) {
                        float nre[4], nim[4];
                        #pragma unroll
                        for (int p = 0; p < 2; ++p) {
                            nre[p]   = U00r*re[p]-U00i*im[p] + U01r*re[p+2]-U01i*im[p+2];
                            nim[p]   = U00r*im[p]+U00i*re[p] + U01r*im[p+2]+U01i*re[p+2];
                            nre[p+2] = U10r*re[p]-U10i*im[p] + U11r*re[p+2]-U11i*im[p+2];
                            nim[p+2] = U10r*im[p]+U10i*re[p] + U11r*im[p+2]+U11i*re[p+2];
                        }
                        #pragma unroll
                        for (int r = 0; r < 4; ++r) { re[r] = nre[r]; im[r] = nim[r]; }
                    } else {
                        float nre[4], nim[4];
                        #pragma unroll
                        for (int p = 0; p < 4; p += 2) {
                            nre[p]   = U00r*re[p]-U00i*im[p] + U01r*re[p+1]-U01i*im[p+1];
                            nim[p]   = U00r*im[p]+U00i*re[p] + U01r*im[p+1]+U01i*re[p+1];
                            nre[p+1] = U10r*re[p]-U10i*im[p] + U11r*re[p+1]-U11i*im[p+1];
                            nim[p+1] = U10r*im[p]+U10i*re[p] + U11r*im[p+1]+U11i*re[p+1];
                        }
                        #pragma unroll
                        for (int r = 0; r < 4; ++r) { re[r] = nre[r]; im[r] = nim[r]; }
                    }
                }

                // composed CNOT ring permutation
                {
                    const float s0r = par ? re[2] : re[0], s0i = par ? im[2] : im[0];
                    const float s1r = par ? re[3] : re[1], s1i = par ? im[3] : im[1];
                    const float s2r = par ? re[1] : re[3], s2i = par ? im[1] : im[3];
                    const float s3r = par ? re[0] : re[2], s3i = par ? im[0] : im[2];
                    re[0] = __shfl(s0r, G, 64);    im[0] = __shfl(s0i, G, 64);
                    re[1] = __shfl(s1r, mapB, 64); im[1] = __shfl(s1i, mapB, 64);
                    re[2] = __shfl(s2r, G, 64);    im[2] = __shfl(s2i, G, 64);
                    re[3] = __shfl(s3r, mapB, 64); im[3] = __shfl(s3i, mapB, 64);
                }
            }

            // <Z_w> reduction
            const float p0 = re[0]*re[0] + im[0]*im[0];
            const float p1 = re[1]*re[1] + im[1]*im[1];
            const float p2 = re[2]*re[2] + im[2]*im[2];
            const float p3 = re[3]*re[3] + im[3]*im[3];
            const float pt = p0 + p1 + p2 + p3;
            float v[8];
            #pragma unroll
            for (int w = 0; w < 6; ++w) v[w] = ((L >> (5 - w)) & 1) ? -pt : pt;
            v[6] = p0 + p1 - p2 - p3;
            v[7] = p0 - p1 + p2 - p3;
            #pragma unroll
            for (int j = 0; j < 4; ++j) {
                const float send = (L & 1) ? v[j] : v[j + 4];
                const float keep = (L & 1) ? v[j + 4] : v[j];
                v[j] = keep + __shfl_xor(send, 1, 64);
            }
            #pragma unroll
            for (int j = 0; j < 2; ++j) {
                const float send = (L & 2) ? v[j] : v[j + 2];
                const float keep = (L & 2) ? v[j + 2] : v[j];
                v[j] = keep + __shfl_xor(send, 2, 64);
            }
            {
                const float send = (L & 4) ? v[0] : v[1];
                const float keep = (L & 4) ? v[1] : v[0];
                v[0] = keep + __shfl_xor(send, 4, 64);
            }
            v[0] += __shfl_xor(v[0], 8, 64);
            v[0] += __shfl_xor(v[0], 16, 64);
            v[0] += __shfl_xor(v[0], 32, 64);
            float z[8];
            #pragma unroll
            for (int w = 0; w < 8; ++w) {
                const int src = ((w & 1) << 2) | (w & 2) | ((w >> 2) & 1);
                z[w] = __shfl(v[0], src, 64);
            }

            // e row = gelu(z@W3 + b3); store exact hi/lo split
            float a0 = b3v.x, a1 = b3v.y, a2 = b3v.z, a3 = b3v.w;
            #pragma unroll
            for (int w = 0; w < 8; ++w) {
                a0 += z[w] * w3r[w].x; a1 += z[w] * w3r[w].y;
                a2 += z[w] * w3r[w].z; a3 += z[w] * w3r[w].w;
            }
            const float4 ev = make_float4(gelu_f(a0), gelu_f(a1), gelu_f(a2), gelu_f(a3));
            short4 hi4, lo4; split4(ev, hi4, lo4);
            *(short4*)&ehi[row][4 * L] = hi4;
            *(short4*)&elo[row][4 * L] = lo4;
        }
    }
    __syncthreads();

    // ================= phase 4: y = e@W4 + b4 + x ; LN ======================
    {
        const int n0 = wid * 192;
        const short* bp4 = W4bt + (size_t)(n0 + r16) * 256 + quad * 8;

        f32x4 acc4[2][12];
        #pragma unroll
        for (int mt = 0; mt < 2; ++mt)
            #pragma unroll
            for (int nt = 0; nt < 12; ++nt) acc4[mt][nt] = (f32x4){0.f, 0.f, 0.f, 0.f};

        for (int kt = 0; kt < 8; ++kt) {
            const bf16x8 a0h = *(const bf16x8*)&ehi[r16][kt * 32 + quad * 8];
            const bf16x8 a0l = *(const bf16x8*)&elo[r16][kt * 32 + quad * 8];
            const bf16x8 a1h = *(const bf16x8*)&ehi[16 + r16][kt * 32 + quad * 8];
            const bf16x8 a1l = *(const bf16x8*)&elo[16 + r16][kt * 32 + quad * 8];
            #pragma unroll
            for (int nt = 0; nt < 12; ++nt) {
                const bf16x8 bfr = *(const bf16x8*)(bp4 + (size_t)nt * 16 * 256 + kt * 32);
                acc4[0][nt] = __builtin_amdgcn_mfma_f32_16x16x32_bf16(a0h, bfr, acc4[0][nt], 0, 0, 0);
                acc4[0][nt] = __builtin_amdgcn_mfma_f32_16x16x32_bf16(a0l, bfr, acc4[0][nt], 0, 0, 0);
                acc4[1][nt] = __builtin_amdgcn_mfma_f32_16x16x32_bf16(a1h, bfr, acc4[1][nt], 0, 0, 0);
                acc4[1][nt] = __builtin_amdgcn_mfma_f32_16x16x32_bf16(a1l, bfr, acc4[1][nt], 0, 0, 0);
            }
        }

        // residual + partial LN sums
        float ps[2][4], pq[2][4];
        #pragma unroll
        for (int mt = 0; mt < 2; ++mt)
            #pragma unroll
            for (int reg = 0; reg < 4; ++reg) { ps[mt][reg] = 0.f; pq[mt][reg] = 0.f; }

        #pragma unroll
        for (int nt = 0; nt < 12; ++nt) {
            const int n = n0 + nt * 16 + r16;
            const float bv = b4[n];
            #pragma unroll
            for (int mt = 0; mt < 2; ++mt) {
                #pragma unroll
                for (int reg = 0; reg < 4; ++reg) {
                    const int row = m0 + 16 * mt + quad * 4 + reg;
                    const float y = acc4[mt][nt][reg] + bv + x[(size_t)row * 768 + n];
                    acc4[mt][nt][reg] = y;
                    ps[mt][reg] += y;
                    pq[mt][reg] += y * y;
                }
            }
        }
        #pragma unroll
        for (int off = 1; off < 16; off <<= 1) {
            #pragma unroll
            for (int mt = 0; mt < 2; ++mt)
                #pragma unroll
                for (int reg = 0; reg < 4; ++reg) {
                    ps[mt][reg] += __shfl_xor(ps[mt][reg], off, 64);
                    pq[mt][reg] += __shfl_xor(pq[mt][reg], off, 64);
                }
        }
        if (r16 == 0) {
            #pragma unroll
            for (int mt = 0; mt < 2; ++mt)
                #pragma unroll
                for (int reg = 0; reg < 4; ++reg) {
                    red[wid][16 * mt + quad * 4 + reg][0] = ps[mt][reg];
                    red[wid][16 * mt + quad * 4 + reg][1] = pq[mt][reg];
                }
        }
        __syncthreads();
        if (tid < 32) {
            const float S = red[0][tid][0] + red[1][tid][0] + red[2][tid][0] + red[3][tid][0];
            const float Q = red[0][tid][1] + red[1][tid][1] + red[2][tid][1] + red[3][tid][1];
            const float mu = S * (1.0f / 768.0f);
            const float var = Q * (1.0f / 768.0f) - mu * mu;
            stats_s[tid][0] = mu;
            stats_s[tid][1] = rsqrtf(var + 1e-5f);
        }
        __syncthreads();

        float mu_r[2][4], rs_r[2][4];
        #pragma unroll
        for (int mt = 0; mt < 2; ++mt)
            #pragma unroll
            for (int reg = 0; reg < 4; ++reg) {
                mu_r[mt][reg] = stats_s[16 * mt + quad * 4 + reg][0];
                rs_r[mt][reg] = stats_s[16 * mt + quad * 4 + reg][1];
            }
        #pragma unroll
        for (int nt = 0; nt < 12; ++nt) {
            const int n = n0 + nt * 16 + r16;
            const float g = gamma[n], bt = beta[n];
            #pragma unroll
            for (int mt = 0; mt < 2; ++mt) {
                #pragma unroll
                for (int reg = 0; reg < 4; ++reg) {
                    const int row = m0 + 16 * mt + quad * 4 + reg;
                    out[(size_t)row * 768 + n] =
                        g * (acc4[mt][nt][reg] - mu_r[mt][reg]) * rs_r[mt][reg] + bt;
                }
            }
        }
    }
}

extern "C" void kernel_launch(void* const* d_in, const int* in_sizes, int n_in,
                              void* d_out, int out_size, void* d_ws, size_t ws_size,
                              hipStream_t stream) {
    (void)n_in; (void)out_size; (void)ws_size;
    const float* x     = (const float*)d_in[0];
    const float* W1    = (const float*)d_in[1];
    const float* b1    = (const float*)d_in[2];
    const float* W2    = (const float*)d_in[3];
    const float* b2    = (const float*)d_in[4];
    const float* qw    = (const float*)d_in[5];
    const float* W3    = (const float*)d_in[6];
    const float* b3    = (const float*)d_in[7];
    const float* W4    = (const float*)d_in[8];
    const float* b4    = (const float*)d_in[9];
    const float* gamma = (const float*)d_in[10];
    const float* beta  = (const float*)d_in[11];
    float* out = (float*)d_out;

    const int D = 768;
    const int B = in_sizes[0] / D;                 // 16384

    short* W1bt = (short*)d_ws;                    // 256x768 bf16
    short* W4bt = W1bt + (size_t)256 * 768;        // 768x256 bf16
    short* W2T  = W4bt + (size_t)768 * 256;        // 16x256 bf16
    float* Cg   = (float*)(W2T + 16 * 256);        // 16x8 f32

    prep_kernel<<<dim3(385), 256, 0, stream>>>(W1, W4, qw, W2, W1bt, W4bt, W2T, Cg);
    fused_kernel<<<dim3(B / 32), 256, 0, stream>>>(
        x, W1bt, b1, W2T, b2, Cg, W3, b3, W4bt, b4, gamma, beta, out);
}